// Round 1
// baseline (187.507 us; speedup 1.0000x reference)
//
#include <hip/hip_runtime.h>

// ---------------------------------------------------------------------------
// CausalSelfAttention (no mask despite the name): y = proj(attn(qkv(x)))
// B=2, T=2048, D=1024, H=16, hd=64. fp32 in/out, bf16 MFMA internally.
//
// ws layout (needs >= 48 MB):
//   [ 0, 8)MB  xb   : x as bf16            [4096][1024]
//   [ 8,14)MB  wab  : w_attn as bf16       [3072][1024]
//   [14,16)MB  wpb  : w_proj as bf16       [1024][1024]
//   [16,24)MB  Qb   : Q bf16               [32(bh)][2048][64]  (q pre-scaled? no: raw)
//   [24,32)MB  Kb   : K bf16               [32(bh)][2048][64]
//   [32,40)MB  Vtb  : V^T bf16             [32(bh)][64][2048]
//   [40,48)MB  Ob   : attn out bf16        [4096][1024]  (b,t,(h d))
// ---------------------------------------------------------------------------

typedef unsigned short u16;
typedef __bf16  bf16x8 __attribute__((ext_vector_type(8)));
typedef float   f32x4  __attribute__((ext_vector_type(4)));
typedef unsigned short u16x8 __attribute__((ext_vector_type(8)));

__device__ __forceinline__ u16 f2bf(float f) {
  __bf16 h = (__bf16)f;
  return __builtin_bit_cast(unsigned short, h);
}
__device__ __forceinline__ float bf2f(u16 u) {
  unsigned int x = ((unsigned int)u) << 16;
  return __builtin_bit_cast(float, x);
}
__device__ __forceinline__ f32x4 mfma16(u16x8 a, u16x8 b, f32x4 c) {
  return __builtin_amdgcn_mfma_f32_16x16x32_bf16(
      __builtin_bit_cast(bf16x8, a), __builtin_bit_cast(bf16x8, b), c, 0, 0, 0);
}

// async global->LDS, 16B per lane. lds dest: wave-uniform base + lane*16.
__device__ __forceinline__ void gld_lds16(const void* g, void* l) {
  __builtin_amdgcn_global_load_lds(
      (const __attribute__((address_space(1))) void*)g,
      (__attribute__((address_space(3))) void*)l, 16, 0, 0);
}

// ---------------------------------------------------------------------------
// fp32 -> bf16 convert (vectorized, memory-bound)
// ---------------------------------------------------------------------------
__global__ __launch_bounds__(256) void cvt_f32_bf16(
    const float* __restrict__ in, u16* __restrict__ out, int n4) {
  int i = blockIdx.x * blockDim.x + threadIdx.x;
  if (i < n4) {
    float4 v = ((const float4*)in)[i];
    ushort4 o;
    o.x = f2bf(v.x); o.y = f2bf(v.y); o.z = f2bf(v.z); o.w = f2bf(v.w);
    ((ushort4*)out)[i] = o;
  }
}

// ---------------------------------------------------------------------------
// m97-structure GEMM tile: C[128x128] = A[128xK] * B[128xK]^T (both K-major),
// 4 waves (2x2 of 64x64), BK=32, global_load_lds staging, 16x16x32 bf16 MFMA.
// ---------------------------------------------------------------------------
__device__ __forceinline__ void gemm_tile(
    const u16* __restrict__ A, const u16* __restrict__ B, const int K,
    const int bm, const int bn, u16* As, u16* Bs, f32x4 acc[4][4]) {
  const int tid  = threadIdx.x;
  const int lane = tid & 63;
  const int wv   = tid >> 6;
  const int wr   = wv >> 1, wc = wv & 1;
  const int g    = lane >> 4, lc = lane & 15;
  const int nk   = K >> 5;
  for (int kt = 0; kt < nk; ++kt) {
    __syncthreads();  // protect LDS reuse
#pragma unroll
    for (int it = 0; it < 2; ++it) {
      const int c  = it * 4 + wv;         // 1KB chunk id (0..7)
      const int r  = c * 16 + (lane >> 2);  // tile row 0..127
      const int cc = lane & 3;              // 16B chunk within 64B row
      gld_lds16(A + (size_t)(bm + r) * K + kt * 32 + cc * 8, As + c * 512);
      gld_lds16(B + (size_t)(bn + r) * K + kt * 32 + cc * 8, Bs + c * 512);
    }
    __syncthreads();  // barrier drains vmcnt -> tiles ready
    u16x8 af[4], bfv[4];
#pragma unroll
    for (int mt = 0; mt < 4; ++mt)
      af[mt] = *(const u16x8*)(As + (wr * 64 + mt * 16 + lc) * 32 + g * 8);
#pragma unroll
    for (int nt = 0; nt < 4; ++nt)
      bfv[nt] = *(const u16x8*)(Bs + (wc * 64 + nt * 16 + lc) * 32 + g * 8);
#pragma unroll
    for (int mt = 0; mt < 4; ++mt)
#pragma unroll
      for (int nt = 0; nt < 4; ++nt)
        acc[mt][nt] = mfma16(af[mt], bfv[nt], acc[mt][nt]);
  }
}

// ---------------------------------------------------------------------------
// GEMM1: qkv = x @ w_attn^T + b_attn, scattered into Q / K / V^T (bf16)
// grid (24, 32): x = N-tile (3072/128), y = M-tile (4096/128)
// ---------------------------------------------------------------------------
__global__ __launch_bounds__(256) void qkv_gemm(
    const u16* __restrict__ xb, const u16* __restrict__ wab,
    const float* __restrict__ b_attn,
    u16* __restrict__ Qb, u16* __restrict__ Kb, u16* __restrict__ Vtb) {
  __shared__ u16 As[128 * 32], Bs[128 * 32];
  f32x4 acc[4][4];
#pragma unroll
  for (int i = 0; i < 4; ++i)
#pragma unroll
    for (int j = 0; j < 4; ++j) acc[i][j] = f32x4{0.f, 0.f, 0.f, 0.f};

  const int bn0 = blockIdx.x * 128, bm0 = blockIdx.y * 128;
  gemm_tile(xb, wab, 1024, bm0, bn0, As, Bs, acc);

  const int tid = threadIdx.x, lane = tid & 63, wv = tid >> 6;
  const int wr = wv >> 1, wc = wv & 1, g = lane >> 4, lc = lane & 15;
#pragma unroll
  for (int nt = 0; nt < 4; ++nt) {
    const int n    = bn0 + wc * 64 + nt * 16 + lc;
    const float bi = b_attn[n];
    const int sec  = n >> 10;        // 0=q 1=k 2=v (uniform per block)
    const int rem  = n & 1023;
    const int h    = rem >> 6, d = rem & 63;
#pragma unroll
    for (int mt = 0; mt < 4; ++mt) {
      const int m0  = bm0 + wr * 64 + mt * 16 + g * 4;  // multiple of 4
      const int b   = m0 >> 11;
      const int t0  = m0 & 2047;
      const int bhh = b * 16 + h;
      u16 v[4];
#pragma unroll
      for (int r = 0; r < 4; ++r) v[r] = f2bf(acc[mt][nt][r] + bi);
      if (sec == 0) {
#pragma unroll
        for (int r = 0; r < 4; ++r)
          Qb[((size_t)bhh * 2048 + t0 + r) * 64 + d] = v[r];
      } else if (sec == 1) {
#pragma unroll
        for (int r = 0; r < 4; ++r)
          Kb[((size_t)bhh * 2048 + t0 + r) * 64 + d] = v[r];
      } else {  // V stored transposed: Vt[bh][d][t], 4 consecutive t -> 8B store
        ushort4 pk; pk.x = v[0]; pk.y = v[1]; pk.z = v[2]; pk.w = v[3];
        *(ushort4*)(Vtb + ((size_t)bhh * 64 + d) * 2048 + t0) = pk;
      }
    }
  }
}

// ---------------------------------------------------------------------------
// Flash attention. grid (16, 32): x = Q-tile (2048/128), y = bh.
// 4 waves, 32 q-rows each. KVBLK=64. K/Vt tiles in LDS, XOR-swizzled via
// pre-swizzled global source (linear LDS dest for global_load_lds).
// ---------------------------------------------------------------------------
__global__ __launch_bounds__(256) void attn_kernel(
    const u16* __restrict__ Qb, const u16* __restrict__ Kb,
    const u16* __restrict__ Vtb, u16* __restrict__ Ob) {
  __shared__ u16 Ks[64 * 64];        // [kv_j][d], rows swizzled
  __shared__ u16 Vs[64 * 64];        // [d][kv_j], rows swizzled
  __shared__ u16 Ps[4][32 * 72];     // per-wave P, pitch 72 (conflict-free)

  const int tid = threadIdx.x, lane = tid & 63, wv = tid >> 6;
  const int g = lane >> 4, lc = lane & 15;
  const int bh = blockIdx.y;
  const int qbase = blockIdx.x * 128 + wv * 32;

  const u16* Qp = Qb  + (size_t)bh * (2048 * 64);
  const u16* Kp = Kb  + (size_t)bh * (2048 * 64);
  const u16* Vp = Vtb + (size_t)bh * (64 * 2048);

  // Q fragments in registers, pre-scaled by 1/sqrt(64) * log2(e)  (base-2 softmax)
  const float qscale = 0.125f * 1.44269504088896f;
  u16x8 qa[2][2];
#pragma unroll
  for (int mt = 0; mt < 2; ++mt)
#pragma unroll
    for (int kb = 0; kb < 2; ++kb) {
      u16x8 raw = *(const u16x8*)(Qp + (size_t)(qbase + mt * 16 + lc) * 64 + kb * 32 + g * 8);
      u16x8 sc;
#pragma unroll
      for (int j = 0; j < 8; ++j) sc[j] = f2bf(bf2f(raw[j]) * qscale);
      qa[mt][kb] = sc;
    }

  f32x4 of[2][4];
  float m_run[2][4], l_run[2][4];
#pragma unroll
  for (int mt = 0; mt < 2; ++mt) {
#pragma unroll
    for (int dt = 0; dt < 4; ++dt) of[mt][dt] = f32x4{0.f, 0.f, 0.f, 0.f};
#pragma unroll
    for (int r = 0; r < 4; ++r) { m_run[mt][r] = -3.0e38f; l_run[mt][r] = 0.f; }
  }

  for (int kv = 0; kv < 2048; kv += 64) {
    __syncthreads();  // prior tile fully consumed
    // stage K[64][64] and Vt[64][64]; source pre-swizzled: byte ^= (row&7)<<4
#pragma unroll
    for (int it = 0; it < 2; ++it) {
      const int c   = it * 4 + wv;
      const int i   = c * 64 + lane;
      const int r   = i >> 3;               // tile row (128B rows)
      const int cb  = (i & 7) * 16;
      const int cbs = cb ^ ((r & 7) << 4);
      gld_lds16((const char*)Kp + (size_t)(kv + r) * 128 + cbs, (char*)Ks + c * 1024);
      gld_lds16((const char*)Vp + (size_t)r * 4096 + (size_t)kv * 2 + cbs,
                (char*)Vs + c * 1024);
    }
    __syncthreads();

    // ---- S = (Q*scale) K^T, base-2 units -------------------------------
    f32x4 s[2][4];
#pragma unroll
    for (int jt = 0; jt < 4; ++jt) {
      const int r  = jt * 16 + lc;
      const int c0 = (g * 16)      ^ ((r & 7) << 4);
      const int c1 = (64 + g * 16) ^ ((r & 7) << 4);
      u16x8 k0 = *(const u16x8*)((const char*)Ks + r * 128 + c0);
      u16x8 k1 = *(const u16x8*)((const char*)Ks + r * 128 + c1);
#pragma unroll
      for (int mt = 0; mt < 2; ++mt) {
        f32x4 a = f32x4{0.f, 0.f, 0.f, 0.f};
        a = mfma16(qa[mt][0], k0, a);
        a = mfma16(qa[mt][1], k1, a);
        s[mt][jt] = a;
      }
    }

    // ---- online softmax (rows live in this lane's (g,reg); cols across 16 lanes)
    float scl[2][4];
#pragma unroll
    for (int mt = 0; mt < 2; ++mt)
#pragma unroll
      for (int r = 0; r < 4; ++r) {
        float v = fmaxf(fmaxf(s[mt][0][r], s[mt][1][r]),
                        fmaxf(s[mt][2][r], s[mt][3][r]));
        v = fmaxf(v, __shfl_xor(v, 1));
        v = fmaxf(v, __shfl_xor(v, 2));
        v = fmaxf(v, __shfl_xor(v, 4));
        v = fmaxf(v, __shfl_xor(v, 8));
        const float mn = fmaxf(m_run[mt][r], v);
        scl[mt][r] = __builtin_amdgcn_exp2f(m_run[mt][r] - mn);
        m_run[mt][r] = mn;
      }

    float rs[2][4];
#pragma unroll
    for (int mt = 0; mt < 2; ++mt)
#pragma unroll
      for (int r = 0; r < 4; ++r) rs[mt][r] = 0.f;

    // P = exp2(S - m), write to per-wave LDS (C/D layout -> row-major)
#pragma unroll
    for (int mt = 0; mt < 2; ++mt)
#pragma unroll
      for (int jt = 0; jt < 4; ++jt)
#pragma unroll
        for (int r = 0; r < 4; ++r) {
          const float p = __builtin_amdgcn_exp2f(s[mt][jt][r] - m_run[mt][r]);
          rs[mt][r] += p;
          Ps[wv][(mt * 16 + g * 4 + r) * 72 + jt * 16 + lc] = f2bf(p);
        }

#pragma unroll
    for (int mt = 0; mt < 2; ++mt)
#pragma unroll
      for (int r = 0; r < 4; ++r) {
        float v = rs[mt][r];
        v += __shfl_xor(v, 1);
        v += __shfl_xor(v, 2);
        v += __shfl_xor(v, 4);
        v += __shfl_xor(v, 8);
        l_run[mt][r] = l_run[mt][r] * scl[mt][r] + v;
      }

    // rescale running O
#pragma unroll
    for (int mt = 0; mt < 2; ++mt)
#pragma unroll
      for (int dt = 0; dt < 4; ++dt) {
        f32x4 o = of[mt][dt];
        o[0] *= scl[mt][0]; o[1] *= scl[mt][1];
        o[2] *= scl[mt][2]; o[3] *= scl[mt][3];
        of[mt][dt] = o;
      }

    // wave-local fence: P writes (same wave) visible before P reads
    asm volatile("s_waitcnt lgkmcnt(0)" ::: "memory");

    // ---- O += P V  (A = P from Ps, B = V from swizzled Vs (V^T layout)) --
    u16x8 pf[2][2];
#pragma unroll
    for (int mt = 0; mt < 2; ++mt)
#pragma unroll
      for (int kb = 0; kb < 2; ++kb)
        pf[mt][kb] = *(const u16x8*)((const char*)&Ps[wv][0] +
                                     (mt * 16 + lc) * 144 + kb * 64 + g * 16);
#pragma unroll
    for (int dt = 0; dt < 4; ++dt) {
      const int r  = dt * 16 + lc;
      const int c0 = (g * 16)      ^ ((r & 7) << 4);
      const int c1 = (64 + g * 16) ^ ((r & 7) << 4);
      u16x8 v0 = *(const u16x8*)((const char*)Vs + r * 128 + c0);
      u16x8 v1 = *(const u16x8*)((const char*)Vs + r * 128 + c1);
#pragma unroll
      for (int mt = 0; mt < 2; ++mt) {
        f32x4 o = of[mt][dt];
        o = mfma16(pf[mt][0], v0, o);
        o = mfma16(pf[mt][1], v1, o);
        of[mt][dt] = o;
      }
    }
  }

  // epilogue: O /= l, write bf16 to Ob[b][t][(h d)]
  const int b = bh >> 4, h = bh & 15;
#pragma unroll
  for (int mt = 0; mt < 2; ++mt)
#pragma unroll
    for (int r = 0; r < 4; ++r) {
      const float inv = 1.0f / l_run[mt][r];
      const int t = qbase + mt * 16 + g * 4 + r;
      const size_t base = ((size_t)b * 2048 + t) * 1024 + h * 64;
#pragma unroll
      for (int dt = 0; dt < 4; ++dt)
        Ob[base + dt * 16 + lc] = f2bf(of[mt][dt][r] * inv);
    }
}

// ---------------------------------------------------------------------------
// GEMM2: y = O @ w_proj^T + b_proj (fp32 out). grid (8, 32).
// ---------------------------------------------------------------------------
__global__ __launch_bounds__(256) void proj_gemm(
    const u16* __restrict__ Ob, const u16* __restrict__ wpb,
    const float* __restrict__ b_proj, float* __restrict__ y) {
  __shared__ u16 As[128 * 32], Bs[128 * 32];
  f32x4 acc[4][4];
#pragma unroll
  for (int i = 0; i < 4; ++i)
#pragma unroll
    for (int j = 0; j < 4; ++j) acc[i][j] = f32x4{0.f, 0.f, 0.f, 0.f};

  const int bn0 = blockIdx.x * 128, bm0 = blockIdx.y * 128;
  gemm_tile(Ob, wpb, 1024, bm0, bn0, As, Bs, acc);

  const int tid = threadIdx.x, lane = tid & 63, wv = tid >> 6;
  const int wr = wv >> 1, wc = wv & 1, g = lane >> 4, lc = lane & 15;
#pragma unroll
  for (int nt = 0; nt < 4; ++nt) {
    const int n    = bn0 + wc * 64 + nt * 16 + lc;
    const float bi = b_proj[n];
#pragma unroll
    for (int mt = 0; mt < 4; ++mt) {
      const int m0 = bm0 + wr * 64 + mt * 16 + g * 4;
#pragma unroll
      for (int r = 0; r < 4; ++r)
        y[(size_t)(m0 + r) * 1024 + n] = acc[mt][nt][r] + bi;
    }
  }
}

// ---------------------------------------------------------------------------
extern "C" void kernel_launch(void* const* d_in, const int* in_sizes, int n_in,
                              void* d_out, int out_size, void* d_ws, size_t ws_size,
                              hipStream_t stream) {
  (void)in_sizes; (void)n_in; (void)out_size; (void)ws_size;
  const float* x      = (const float*)d_in[0];
  const float* w_attn = (const float*)d_in[1];
  const float* b_attn = (const float*)d_in[2];
  const float* w_proj = (const float*)d_in[3];
  const float* b_proj = (const float*)d_in[4];
  float* y = (float*)d_out;

  char* ws = (char*)d_ws;
  const size_t MB = 1024 * 1024;
  u16* xb  = (u16*)(ws);             // 8 MB
  u16* wab = (u16*)(ws + 8  * MB);   // 6 MB
  u16* wpb = (u16*)(ws + 14 * MB);   // 2 MB
  u16* Qb  = (u16*)(ws + 16 * MB);   // 8 MB
  u16* Kb  = (u16*)(ws + 24 * MB);   // 8 MB
  u16* Vtb = (u16*)(ws + 32 * MB);   // 8 MB
  u16* Ob  = (u16*)(ws + 40 * MB);   // 8 MB

  cvt_f32_bf16<<<(4096 * 1024 / 4) / 256, 256, 0, stream>>>(x,      xb,  4096 * 1024 / 4);
  cvt_f32_bf16<<<(3072 * 1024 / 4) / 256, 256, 0, stream>>>(w_attn, wab, 3072 * 1024 / 4);
  cvt_f32_bf16<<<(1024 * 1024 / 4) / 256, 256, 0, stream>>>(w_proj, wpb, 1024 * 1024 / 4);

  qkv_gemm<<<dim3(24, 32), 256, 0, stream>>>(xb, wab, b_attn, Qb, Kb, Vtb);
  attn_kernel<<<dim3(16, 32), 256, 0, stream>>>(Qb, Kb, Vtb, Ob);
  proj_gemm<<<dim3(8, 32), 256, 0, stream>>>(Ob, wpb, b_proj, y);
}

// Round 2
// 130.907 us; speedup vs baseline: 1.4324x; 1.4324x over previous
//
#include <hip/hip_runtime.h>

// ---------------------------------------------------------------------------
// y = proj(attn(qkv(x))), B=2, T=2048, D=1024, H=16, hd=64. No causal mask.
// fp32 in/out, bf16 MFMA internally.
//
// ws layout (48 MB):
//   [ 0, 8)MB  xb  : x bf16 [4096][1024]
//   [ 8,14)MB  wab : w_attn bf16 [3072][1024]
//   [14,16)MB  wpb : w_proj bf16 [1024][1024]
//   [16,24)MB  Qb  : Q bf16 [32 bh][2048][64] row-major
//   [24,32)MB  Kg  : K bf16 chunk-transposed [bh][tile32][c8][r64][e8]
//   [32,40)MB  Vg  : V bf16 chunk-transposed [bh][tile32][c8][d64][e8] (c along kv)
//   [40,48)MB  Ob  : attn out bf16 [4096][1024]
// ---------------------------------------------------------------------------

typedef unsigned short u16;
typedef __bf16  bf16x8 __attribute__((ext_vector_type(8)));
typedef float   f32x4  __attribute__((ext_vector_type(4)));
typedef float   f32x16 __attribute__((ext_vector_type(16)));
typedef unsigned short u16x8 __attribute__((ext_vector_type(8)));
typedef unsigned int   u32x4 __attribute__((ext_vector_type(4)));

__device__ __forceinline__ u16 f2bf(float f) {
  __bf16 h = (__bf16)f;
  return __builtin_bit_cast(unsigned short, h);
}
__device__ __forceinline__ float bf2f(u16 u) {
  unsigned int x = ((unsigned int)u) << 16;
  return __builtin_bit_cast(float, x);
}
__device__ __forceinline__ f32x4 mfma16(u16x8 a, u16x8 b, f32x4 c) {
  return __builtin_amdgcn_mfma_f32_16x16x32_bf16(
      __builtin_bit_cast(bf16x8, a), __builtin_bit_cast(bf16x8, b), c, 0, 0, 0);
}
__device__ __forceinline__ f32x16 mfma32(u16x8 a, u16x8 b, f32x16 c) {
  return __builtin_amdgcn_mfma_f32_32x32x16_bf16(
      __builtin_bit_cast(bf16x8, a), __builtin_bit_cast(bf16x8, b), c, 0, 0, 0);
}
__device__ __forceinline__ void gld_lds16(const void* g, void* l) {
  __builtin_amdgcn_global_load_lds(
      (const __attribute__((address_space(1))) void*)g,
      (__attribute__((address_space(3))) void*)l, 16, 0, 0);
}
// pack two f32 -> bf16x2 word (v_cvt_pk_bf16_f32, T12 recipe)
__device__ __forceinline__ unsigned pack_bf2(float lo, float hi) {
  unsigned r;
  asm("v_cvt_pk_bf16_f32 %0, %1, %2" : "=v"(r) : "v"(lo), "v"(hi));
  return r;
}
// Build B-frag words for k-slot: own pair-words (Wl covers kv hi*4+{..}, Wh the +8 pair).
// After: Wl = word(e=2w low), Wh = word(e high). Direction-unambiguous shfl version.
__device__ __forceinline__ void xhalf(unsigned &Wl, unsigned &Wh, bool hib) {
  unsigned sel = hib ? Wl : Wh;                  // what the partner half needs
  unsigned p   = (unsigned)__shfl_xor((int)sel, 32);
  unsigned nl  = hib ? p  : Wl;
  unsigned nh  = hib ? Wh : p;
  Wl = nl; Wh = nh;
}

// ---------------------------------------------------------------------------
__global__ __launch_bounds__(256) void cvt_f32_bf16(
    const float* __restrict__ in, u16* __restrict__ out, int n4) {
  int i = blockIdx.x * blockDim.x + threadIdx.x;
  if (i < n4) {
    float4 v = ((const float4*)in)[i];
    ushort4 o;
    o.x = f2bf(v.x); o.y = f2bf(v.y); o.z = f2bf(v.z); o.w = f2bf(v.w);
    ((ushort4*)out)[i] = o;
  }
}

// ---------------------------------------------------------------------------
// m97-structure GEMM tile: C[128x128] = A[128xK] * B[128xK]^T, 4 waves, BK=32.
// ---------------------------------------------------------------------------
__device__ __forceinline__ void gemm_tile(
    const u16* __restrict__ A, const u16* __restrict__ B, const int K,
    const int bm, const int bn, u16* As, u16* Bs, f32x4 acc[4][4]) {
  const int tid  = threadIdx.x;
  const int lane = tid & 63;
  const int wv   = tid >> 6;
  const int wr   = wv >> 1, wc = wv & 1;
  const int g    = lane >> 4, lc = lane & 15;
  const int nk   = K >> 5;
  for (int kt = 0; kt < nk; ++kt) {
    __syncthreads();
#pragma unroll
    for (int it = 0; it < 2; ++it) {
      const int c  = it * 4 + wv;
      const int r  = c * 16 + (lane >> 2);
      const int cc = lane & 3;
      gld_lds16(A + (size_t)(bm + r) * K + kt * 32 + cc * 8, As + c * 512);
      gld_lds16(B + (size_t)(bn + r) * K + kt * 32 + cc * 8, Bs + c * 512);
    }
    __syncthreads();
    u16x8 af[4], bfv[4];
#pragma unroll
    for (int mt = 0; mt < 4; ++mt)
      af[mt] = *(const u16x8*)(As + (wr * 64 + mt * 16 + lc) * 32 + g * 8);
#pragma unroll
    for (int nt = 0; nt < 4; ++nt)
      bfv[nt] = *(const u16x8*)(Bs + (wc * 64 + nt * 16 + lc) * 32 + g * 8);
#pragma unroll
    for (int mt = 0; mt < 4; ++mt)
#pragma unroll
      for (int nt = 0; nt < 4; ++nt)
        acc[mt][nt] = mfma16(af[mt], bfv[nt], acc[mt][nt]);
  }
}

// ---------------------------------------------------------------------------
// GEMM1: qkv = x @ w_attn^T + b_attn -> Q row-major, K/V chunk-transposed
// ---------------------------------------------------------------------------
__global__ __launch_bounds__(256) void qkv_gemm(
    const u16* __restrict__ xb, const u16* __restrict__ wab,
    const float* __restrict__ b_attn,
    u16* __restrict__ Qb, u16* __restrict__ Kg, u16* __restrict__ Vg) {
  __shared__ u16 As[128 * 32], Bs[128 * 32];
  f32x4 acc[4][4];
#pragma unroll
  for (int i = 0; i < 4; ++i)
#pragma unroll
    for (int j = 0; j < 4; ++j) acc[i][j] = f32x4{0.f, 0.f, 0.f, 0.f};

  const int bn0 = blockIdx.x * 128, bm0 = blockIdx.y * 128;
  gemm_tile(xb, wab, 1024, bm0, bn0, As, Bs, acc);

  const int tid = threadIdx.x, lane = tid & 63, wv = tid >> 6;
  const int wr = wv >> 1, wc = wv & 1, g = lane >> 4, lc = lane & 15;
#pragma unroll
  for (int nt = 0; nt < 4; ++nt) {
    const int n    = bn0 + wc * 64 + nt * 16 + lc;
    const float bi = b_attn[n];
    const int sec  = n >> 10;        // 0=q 1=k 2=v
    const int rem  = n & 1023;
    const int h    = rem >> 6, d = rem & 63;
#pragma unroll
    for (int mt = 0; mt < 4; ++mt) {
      const int m0  = bm0 + wr * 64 + mt * 16 + g * 4;  // multiple of 4
      const int b   = m0 >> 11;
      const int t0  = m0 & 2047;
      const int bhh = b * 16 + h;
      u16 v[4];
#pragma unroll
      for (int r = 0; r < 4; ++r) v[r] = f2bf(acc[mt][nt][r] + bi);
      if (sec == 0) {
#pragma unroll
        for (int r = 0; r < 4; ++r)
          Qb[((size_t)bhh * 2048 + t0 + r) * 64 + d] = v[r];
      } else if (sec == 1) {
        // Kg[bh][t>>6][c=d>>3][r=t&63][e=d&7]
        const size_t kb = ((size_t)bhh * 32 + (t0 >> 6)) * 4096 +
                          (size_t)((d >> 3) * 64 + (t0 & 63)) * 8 + (d & 7);
#pragma unroll
        for (int r = 0; r < 4; ++r) Kg[kb + (size_t)r * 8] = v[r];
      } else {
        // Vg[bh][kv>>6][c=(kv&63)>>3][row=d][e=kv&7]; 4 consecutive kv -> 8B store
        const size_t vb = ((size_t)bhh * 32 + (t0 >> 6)) * 4096 +
                          (size_t)((((t0 & 63) >> 3) * 64) + d) * 8 + (t0 & 7);
        ushort4 pk; pk.x = v[0]; pk.y = v[1]; pk.z = v[2]; pk.w = v[3];
        *(ushort4*)(Vg + vb) = pk;
      }
    }
  }
}

// ---------------------------------------------------------------------------
// Flash attention, swapped-QK^T 32x32 MFMA, in-register P (T12), dbuf K/V.
// grid (16, 32): x = Q-tile (2048/128), y = bh. 4 waves x 32 q-rows.
// ---------------------------------------------------------------------------
__global__ __launch_bounds__(256) void attn_kernel(
    const u16* __restrict__ Qb, const u16* __restrict__ Kg,
    const u16* __restrict__ Vg, u16* __restrict__ Ob) {
  __shared__ u16 Ks[2][4096];   // [buf][c=8][row=64][e=8], 8KB per buf
  __shared__ u16 Vs[2][4096];

  const int tid = threadIdx.x, lane = tid & 63, wv = tid >> 6;
  const int hi = lane >> 5, l5 = lane & 31;
  const bool hib = (hi != 0);
  const int bh = blockIdx.y;
  const int qrow = blockIdx.x * 128 + wv * 32 + l5;

  const u16* Qp = Qb + ((size_t)bh * 2048 + qrow) * 64;
  const u16* Kt = Kg + (size_t)bh * 131072;   // 32 tiles * 4096
  const u16* Vt = Vg + (size_t)bh * 131072;

  // Q fragments (B-operand: col=q=l5, k=ks*16+hi*8+e), prescaled to base-2
  const float qscale = 0.125f * 1.44269504088896f;
  u16x8 qf[4];
#pragma unroll
  for (int ks = 0; ks < 4; ++ks) {
    u16x8 raw = *(const u16x8*)(Qp + ks * 16 + hi * 8);
    u16x8 sc;
#pragma unroll
    for (int j = 0; j < 8; ++j) sc[j] = f2bf(bf2f(raw[j]) * qscale);
    qf[ks] = sc;
  }

  f32x16 o0, o1;
#pragma unroll
  for (int i = 0; i < 16; ++i) { o0[i] = 0.f; o1[i] = 0.f; }
  float m_run = -3.0e38f, l_run = 0.f;

  // prologue: stage tile 0 -> buf 0 (chunk-transposed global = linear copy)
#pragma unroll
  for (int pass = 0; pass < 2; ++pass) {
    const int cb = (pass * 4 + wv) * 64;
    gld_lds16(Kt + (size_t)(cb + lane) * 8, &Ks[0][cb * 8]);
    gld_lds16(Vt + (size_t)(cb + lane) * 8, &Vs[0][cb * 8]);
  }
  __syncthreads();

  for (int it = 0; it < 32; ++it) {
    const int cur = it & 1;
    if (it < 31) {   // stage next tile into other buffer (hidden under compute)
      const u16* Kn = Kt + (size_t)(it + 1) * 4096;
      const u16* Vn = Vt + (size_t)(it + 1) * 4096;
#pragma unroll
      for (int pass = 0; pass < 2; ++pass) {
        const int cb = (pass * 4 + wv) * 64;
        gld_lds16(Kn + (size_t)(cb + lane) * 8, &Ks[cur ^ 1][cb * 8]);
        gld_lds16(Vn + (size_t)(cb + lane) * 8, &Vs[cur ^ 1][cb * 8]);
      }
    }

    // ---- S^T = K Q^T (A=K rows kv, B=Q cols q). s0: kv 0..31, s1: 32..63.
    f32x16 s0, s1;
#pragma unroll
    for (int i = 0; i < 16; ++i) { s0[i] = 0.f; s1[i] = 0.f; }
    __builtin_amdgcn_s_setprio(1);
#pragma unroll
    for (int ks = 0; ks < 4; ++ks) {
      const int c = (ks * 2 + hi) * 64;
      const u16x8 kf0 = *(const u16x8*)(&Ks[cur][(c + l5) * 8]);
      const u16x8 kf1 = *(const u16x8*)(&Ks[cur][(c + 32 + l5) * 8]);
      s0 = mfma32(kf0, qf[ks], s0);
      s1 = mfma32(kf1, qf[ks], s1);
    }
    __builtin_amdgcn_s_setprio(0);

    // ---- online softmax; q-row = l5 (lane-local across both halves)
    float mx = s0[0];
#pragma unroll
    for (int i = 1; i < 16; ++i) mx = fmaxf(mx, s0[i]);
#pragma unroll
    for (int i = 0; i < 16; ++i) mx = fmaxf(mx, s1[i]);
    mx = fmaxf(mx, __shfl_xor(mx, 32));
    if (!__all(mx - m_run <= 8.0f)) {   // T13 defer-max
      const float mn  = fmaxf(m_run, mx);
      const float scl = __builtin_amdgcn_exp2f(m_run - mn);
      m_run = mn;
      l_run *= scl;
#pragma unroll
      for (int i = 0; i < 16; ++i) { o0[i] *= scl; o1[i] *= scl; }
    }
    float rs = 0.f;
#pragma unroll
    for (int i = 0; i < 16; ++i) {
      s0[i] = __builtin_amdgcn_exp2f(s0[i] - m_run); rs += s0[i];
    }
#pragma unroll
    for (int i = 0; i < 16; ++i) {
      s1[i] = __builtin_amdgcn_exp2f(s1[i] - m_run); rs += s1[i];
    }
    rs += __shfl_xor(rs, 32);
    l_run += rs;

    // ---- P frags (in-register) + PV (O^T accumulate) -------------------
    __builtin_amdgcn_s_setprio(1);
#pragma unroll
    for (int kvt = 0; kvt < 2; ++kvt) {
      const f32x16 sp = kvt ? s1 : s0;
      unsigned W0 = pack_bf2(sp[0],  sp[1]);
      unsigned W1 = pack_bf2(sp[2],  sp[3]);
      unsigned W2 = pack_bf2(sp[4],  sp[5]);
      unsigned W3 = pack_bf2(sp[6],  sp[7]);
      unsigned W4 = pack_bf2(sp[8],  sp[9]);
      unsigned W5 = pack_bf2(sp[10], sp[11]);
      unsigned W6 = pack_bf2(sp[12], sp[13]);
      unsigned W7 = pack_bf2(sp[14], sp[15]);
      xhalf(W0, W2, hib);
      xhalf(W1, W3, hib);
      xhalf(W4, W6, hib);
      xhalf(W5, W7, hib);
      u32x4 t0; t0[0] = W0; t0[1] = W1; t0[2] = W2; t0[3] = W3;
      u32x4 t1; t1[0] = W4; t1[1] = W5; t1[2] = W6; t1[3] = W7;
      const u16x8 pf0 = __builtin_bit_cast(u16x8, t0);  // k-slot kv kvt*32+[0,16)
      const u16x8 pf1 = __builtin_bit_cast(u16x8, t1);  // k-slot kv kvt*32+[16,32)
      // A = Vt rows d, k = kv (chunk c = kvt*4 + ks2*2 + hi)
      {
        const u16x8 vf0 = *(const u16x8*)(&Vs[cur][((kvt * 4 + hi) * 64 + l5) * 8]);
        const u16x8 vf1 = *(const u16x8*)(&Vs[cur][((kvt * 4 + 2 + hi) * 64 + l5) * 8]);
        o0 = mfma32(vf0, pf0, o0);
        o0 = mfma32(vf1, pf1, o0);
      }
      {
        const u16x8 vf0 = *(const u16x8*)(&Vs[cur][((kvt * 4 + hi) * 64 + 32 + l5) * 8]);
        const u16x8 vf1 = *(const u16x8*)(&Vs[cur][((kvt * 4 + 2 + hi) * 64 + 32 + l5) * 8]);
        o1 = mfma32(vf0, pf0, o1);
        o1 = mfma32(vf1, pf1, o1);
      }
    }
    __builtin_amdgcn_s_setprio(0);
    __syncthreads();   // publishes next-tile staging; releases cur buffer
  }

  // ---- epilogue: O^T normalize (lane-local l), write Ob[b][t][(h d)] ----
  const float inv = 1.0f / l_run;
  const int b = bh >> 4, h = bh & 15;
  u16* Op = Ob + ((size_t)b * 2048 + qrow) * 1024 + h * 64;
#pragma unroll
  for (int rq = 0; rq < 4; ++rq) {
    ushort4 pk;
    pk.x = f2bf(o0[rq * 4 + 0] * inv);
    pk.y = f2bf(o0[rq * 4 + 1] * inv);
    pk.z = f2bf(o0[rq * 4 + 2] * inv);
    pk.w = f2bf(o0[rq * 4 + 3] * inv);
    *(ushort4*)(Op + rq * 8 + hi * 4) = pk;
  }
#pragma unroll
  for (int rq = 0; rq < 4; ++rq) {
    ushort4 pk;
    pk.x = f2bf(o1[rq * 4 + 0] * inv);
    pk.y = f2bf(o1[rq * 4 + 1] * inv);
    pk.z = f2bf(o1[rq * 4 + 2] * inv);
    pk.w = f2bf(o1[rq * 4 + 3] * inv);
    *(ushort4*)(Op + 32 + rq * 8 + hi * 4) = pk;
  }
}

// ---------------------------------------------------------------------------
// GEMM2: y = O @ w_proj^T + b_proj (fp32 out). grid (8, 32).
// ---------------------------------------------------------------------------
__global__ __launch_bounds__(256) void proj_gemm(
    const u16* __restrict__ Ob, const u16* __restrict__ wpb,
    const float* __restrict__ b_proj, float* __restrict__ y) {
  __shared__ u16 As[128 * 32], Bs[128 * 32];
  f32x4 acc[4][4];
#pragma unroll
  for (int i = 0; i < 4; ++i)
#pragma unroll
    for (int j = 0; j < 4; ++j) acc[i][j] = f32x4{0.f, 0.f, 0.f, 0.f};

  const int bn0 = blockIdx.x * 128, bm0 = blockIdx.y * 128;
  gemm_tile(Ob, wpb, 1024, bm0, bn0, As, Bs, acc);

  const int tid = threadIdx.x, lane = tid & 63, wv = tid >> 6;
  const int wr = wv >> 1, wc = wv & 1, g = lane >> 4, lc = lane & 15;
#pragma unroll
  for (int nt = 0; nt < 4; ++nt) {
    const int n    = bn0 + wc * 64 + nt * 16 + lc;
    const float bi = b_proj[n];
#pragma unroll
    for (int mt = 0; mt < 4; ++mt) {
      const int m0 = bm0 + wr * 64 + mt * 16 + g * 4;
#pragma unroll
      for (int r = 0; r < 4; ++r)
        y[(size_t)(m0 + r) * 1024 + n] = acc[mt][nt][r] + bi;
    }
  }
}

// ---------------------------------------------------------------------------
extern "C" void kernel_launch(void* const* d_in, const int* in_sizes, int n_in,
                              void* d_out, int out_size, void* d_ws, size_t ws_size,
                              hipStream_t stream) {
  (void)in_sizes; (void)n_in; (void)out_size; (void)ws_size;
  const float* x      = (const float*)d_in[0];
  const float* w_attn = (const float*)d_in[1];
  const float* b_attn = (const float*)d_in[2];
  const float* w_proj = (const float*)d_in[3];
  const float* b_proj = (const float*)d_in[4];
  float* y = (float*)d_out;

  char* ws = (char*)d_ws;
  const size_t MB = 1024 * 1024;
  u16* xb  = (u16*)(ws);             // 8 MB
  u16* wab = (u16*)(ws + 8  * MB);   // 6 MB
  u16* wpb = (u16*)(ws + 14 * MB);   // 2 MB
  u16* Qb  = (u16*)(ws + 16 * MB);   // 8 MB
  u16* Kg  = (u16*)(ws + 24 * MB);   // 8 MB (chunk-transposed)
  u16* Vg  = (u16*)(ws + 32 * MB);   // 8 MB (chunk-transposed)
  u16* Ob  = (u16*)(ws + 40 * MB);   // 8 MB

  cvt_f32_bf16<<<(4096 * 1024 / 4) / 256, 256, 0, stream>>>(x,      xb,  4096 * 1024 / 4);
  cvt_f32_bf16<<<(3072 * 1024 / 4) / 256, 256, 0, stream>>>(w_attn, wab, 3072 * 1024 / 4);
  cvt_f32_bf16<<<(1024 * 1024 / 4) / 256, 256, 0, stream>>>(w_proj, wpb, 1024 * 1024 / 4);

  qkv_gemm<<<dim3(24, 32), 256, 0, stream>>>(xb, wab, b_attn, Qb, Kg, Vg);
  attn_kernel<<<dim3(16, 32), 256, 0, stream>>>(Qb, Kg, Vg, Ob);
  proj_gemm<<<dim3(8, 32), 256, 0, stream>>>(Ob, wpb, b_proj, y);
}